// Round 1
// baseline (469.722 us; speedup 1.0000x reference)
//
#include <hip/hip_runtime.h>

// TensorProduct: N=100000 rows, MUL=64.
// out[row] = concat( o0[320], o1[128*3], o2[64*3] )  -> 896 fp32 per row.
// Strategy: bf16 MFMA (16x16x32). All weight scales folded at prep time:
//   PW0 = PW1/sqrt3 = PW2/sqrt6 = 1/sqrt(128); o0's second term uses PW0/sqrt3.

typedef __bf16 v8bf __attribute__((ext_vector_type(8)));
typedef float f32x4 __attribute__((ext_vector_type(4)));

#define PW0f   0.08838834764831845f   // 1/sqrt(128)
#define PW0S3f 0.05103103630798288f   // 1/sqrt(384)

// ws layout (bf16 elements):
//   B0  [128 x 320] frag-packed at 0      (40960)   K-steps=4, ntiles=20
//   Ba1 [ 64 x 128] frag-packed at 40960  ( 8192)   K-steps=2, ntiles=8
//   Bb0 [ 64 x 128] frag-packed at 49152  ( 8192)
//   Bo2 [ 64 x  64] frag-packed at 57344  ( 4096)   K-steps=2, ntiles=4
// frag addr: element B[k][n] -> ((nt*KS + ks)*64 + q*16 + (n&15))*8 + (k&7)
//   nt=n>>4, ks=k>>5, q=(k>>3)&3  => lane L loads 8 contiguous bf16 (16B).

__global__ __launch_bounds__(256) void prep_weights(
    const float* __restrict__ Wa0, const float* __restrict__ Wb1o0,
    const float* __restrict__ Wa1, const float* __restrict__ Wb0,
    const float* __restrict__ Wo2, unsigned short* __restrict__ ws) {
  int t = blockIdx.x * 256 + threadIdx.x;
  float v;
  int k, n, KS, base;
  if (t < 40960) {                       // B0: rows 0..63 = Wa0*PW0, 64..127 = Wb1o0*PW0/sqrt3
    k = t / 320; n = t % 320; KS = 4; base = 0;
    v = (k < 64) ? Wa0[k * 320 + n] * PW0f : Wb1o0[(k - 64) * 320 + n] * PW0S3f;
  } else if (t < 49152) {                // Ba1
    int tt = t - 40960; k = tt / 128; n = tt % 128; KS = 2; base = 40960;
    v = Wa1[k * 128 + n] * PW0f;
  } else if (t < 57344) {                // Bb0
    int tt = t - 49152; k = tt / 128; n = tt % 128; KS = 2; base = 49152;
    v = Wb0[k * 128 + n] * PW0f;
  } else if (t < 61440) {                // Bo2
    int tt = t - 57344; k = tt / 64; n = tt % 64; KS = 2; base = 57344;
    v = Wo2[k * 64 + n] * PW0f;
  } else {
    return;
  }
  int nt = n >> 4, cc = n & 15, ks = k >> 5, qq = (k >> 3) & 3, j = k & 7;
  int addr = base + ((nt * KS + ks) * 64 + qq * 16 + cc) * 8 + j;
  __bf16 h = (__bf16)v;
  ws[addr] = __builtin_bit_cast(unsigned short, h);
}

// A-fragment LDS index for element (m, k): slot lane = ((k>>3)&3)*16 + m, elem j = k&7
__device__ __forceinline__ int fidx(int k, int m) {
  return (((k >> 5) * 64 + ((k >> 3) & 3) * 16 + m) * 8) + (k & 7);
}

__global__ __launch_bounds__(256) void tp_main(
    const float* __restrict__ in1, const float* __restrict__ in2,
    const float* __restrict__ bias, const unsigned short* __restrict__ wsb,
    float* __restrict__ out, int N) {
  __shared__ __attribute__((aligned(16))) float raw[16 * 256];   // 16 rows of input_1
  __shared__ __attribute__((aligned(16))) float s0v1[16 * 4];    // [s0, v1x, v1y, v1z] per row
  __shared__ __attribute__((aligned(16))) __bf16 f0[2048];       // [x0|x1]  K=128
  __shared__ __attribute__((aligned(16))) __bf16 fsa[1024];      // s_a      K=64
  __shared__ __attribute__((aligned(16))) __bf16 fvb[3][1024];   // v_b[:,k] K=64
  __shared__ __attribute__((aligned(16))) __bf16 fcr[3][1024];   // cross    K=64

  const int tid = threadIdx.x;
  const int r0 = blockIdx.x * 16;

  // ---- Phase 1a: stage inputs ----
  if (tid < 64) {
    int m = tid >> 2, cmp = tid & 3;
    int rr = r0 + m; if (rr >= N) rr = N - 1;
    s0v1[tid] = in2[rr * 4 + cmp];
  }
  for (int i = tid; i < 1024; i += 256) {       // 16 rows x 64 float4
    int row = i >> 6, c4 = i & 63;
    int rr = r0 + row; if (rr >= N) rr = N - 1;
    const float4 v = *(const float4*)(in1 + (size_t)rr * 256 + c4 * 4);
    *(float4*)(raw + row * 256 + c4 * 4) = v;
  }
  __syncthreads();

  // ---- Phase 1b: features -> fragment-order LDS ----
  {
    const int m = tid >> 4;
    const float s0  = s0v1[m * 4 + 0];
    const float v1x = s0v1[m * 4 + 1];
    const float v1y = s0v1[m * 4 + 2];
    const float v1z = s0v1[m * 4 + 3];
#pragma unroll
    for (int du = 0; du < 4; ++du) {
      const int u = (tid & 15) * 4 + du;
      const float sa = raw[m * 256 + u];
      const float b0 = raw[m * 256 + 64 + 3 * u + 0];
      const float b1 = raw[m * 256 + 64 + 3 * u + 1];
      const float b2 = raw[m * 256 + 64 + 3 * u + 2];
      f0[fidx(u, m)]      = (__bf16)(sa * s0);
      f0[fidx(64 + u, m)] = (__bf16)(b0 * v1x + b1 * v1y + b2 * v1z);
      fsa[fidx(u, m)]     = (__bf16)sa;
      fvb[0][fidx(u, m)]  = (__bf16)b0;
      fvb[1][fidx(u, m)]  = (__bf16)b1;
      fvb[2][fidx(u, m)]  = (__bf16)b2;
      fcr[0][fidx(u, m)]  = (__bf16)(b1 * v1z - b2 * v1y);
      fcr[1][fidx(u, m)]  = (__bf16)(b2 * v1x - b0 * v1z);
      fcr[2][fidx(u, m)]  = (__bf16)(b0 * v1y - b1 * v1x);
    }
  }
  __syncthreads();

  // ---- Phase 2: MFMA jobs ----
  const int lane = tid & 63;
  const int wv = tid >> 6;
  const int c = lane & 15, q = lane >> 4;

  const unsigned short* B0p = wsb;
  const unsigned short* Ba1 = wsb + 40960;
  const unsigned short* Bb0 = wsb + 49152;
  const unsigned short* Bo2 = wsb + 57344;

  for (int job = wv; job < 32; job += 4) {
    if (job < 20) {
      // ---- o0 tile: cols nt*16..+15, K=128 ----
      const int nt = job;
      f32x4 acc = {0.f, 0.f, 0.f, 0.f};
#pragma unroll
      for (int ks = 0; ks < 4; ++ks) {
        v8bf a = *(const v8bf*)(f0 + (ks * 64 + lane) * 8);
        v8bf b = *(const v8bf*)(B0p + ((nt * 4 + ks) * 64 + lane) * 8);
        acc = __builtin_amdgcn_mfma_f32_16x16x32_bf16(a, b, acc, 0, 0, 0);
      }
      const int col = nt * 16 + c;
      const float bv = bias[col];
#pragma unroll
      for (int r = 0; r < 4; ++r) {
        const int row = r0 + q * 4 + r;
        if (row < N) out[(size_t)row * 896 + col] = acc[r] + bv;
      }
    } else if (job < 28) {
      // ---- o1 tile: w = jt*16..+15; needs t1 and t2[k] ----
      const int jt = job - 20;
      f32x4 t1 = {0.f, 0.f, 0.f, 0.f};
      f32x4 t2[3];
      t2[0] = t1; t2[1] = t1; t2[2] = t1;
      v8bf ba0 = *(const v8bf*)(Ba1 + ((jt * 2 + 0) * 64 + lane) * 8);
      v8bf ba1 = *(const v8bf*)(Ba1 + ((jt * 2 + 1) * 64 + lane) * 8);
      v8bf bb0 = *(const v8bf*)(Bb0 + ((jt * 2 + 0) * 64 + lane) * 8);
      v8bf bb1 = *(const v8bf*)(Bb0 + ((jt * 2 + 1) * 64 + lane) * 8);
      {
        v8bf a0 = *(const v8bf*)(fsa + (0 * 64 + lane) * 8);
        v8bf a1 = *(const v8bf*)(fsa + (1 * 64 + lane) * 8);
        t1 = __builtin_amdgcn_mfma_f32_16x16x32_bf16(a0, ba0, t1, 0, 0, 0);
        t1 = __builtin_amdgcn_mfma_f32_16x16x32_bf16(a1, ba1, t1, 0, 0, 0);
      }
#pragma unroll
      for (int k = 0; k < 3; ++k) {
        v8bf a0 = *(const v8bf*)(fvb[k] + (0 * 64 + lane) * 8);
        v8bf a1 = *(const v8bf*)(fvb[k] + (1 * 64 + lane) * 8);
        t2[k] = __builtin_amdgcn_mfma_f32_16x16x32_bf16(a0, bb0, t2[k], 0, 0, 0);
        t2[k] = __builtin_amdgcn_mfma_f32_16x16x32_bf16(a1, bb1, t2[k], 0, 0, 0);
      }
#pragma unroll
      for (int r = 0; r < 4; ++r) {
        const int row = q * 4 + r;
        const int gr = r0 + row;
        if (gr < N) {
          const float s0  = s0v1[row * 4 + 0];
          const float v1x = s0v1[row * 4 + 1];
          const float v1y = s0v1[row * 4 + 2];
          const float v1z = s0v1[row * 4 + 3];
          const size_t base = (size_t)gr * 896 + 320 + 3 * (jt * 16 + c);
          out[base + 0] = t1[r] * v1x + t2[0][r] * s0;
          out[base + 1] = t1[r] * v1y + t2[1][r] * s0;
          out[base + 2] = t1[r] * v1z + t2[2][r] * s0;
        }
      }
    } else {
      // ---- o2 tile: w = jt*16..+15 ----
      const int jt = job - 28;
      f32x4 ac[3];
      ac[0] = f32x4{0.f, 0.f, 0.f, 0.f}; ac[1] = ac[0]; ac[2] = ac[0];
      v8bf b0v = *(const v8bf*)(Bo2 + ((jt * 2 + 0) * 64 + lane) * 8);
      v8bf b1v = *(const v8bf*)(Bo2 + ((jt * 2 + 1) * 64 + lane) * 8);
#pragma unroll
      for (int k = 0; k < 3; ++k) {
        v8bf a0 = *(const v8bf*)(fcr[k] + (0 * 64 + lane) * 8);
        v8bf a1 = *(const v8bf*)(fcr[k] + (1 * 64 + lane) * 8);
        ac[k] = __builtin_amdgcn_mfma_f32_16x16x32_bf16(a0, b0v, ac[k], 0, 0, 0);
        ac[k] = __builtin_amdgcn_mfma_f32_16x16x32_bf16(a1, b1v, ac[k], 0, 0, 0);
      }
#pragma unroll
      for (int r = 0; r < 4; ++r) {
        const int row = q * 4 + r;
        const int gr = r0 + row;
        if (gr < N) {
          const size_t base = (size_t)gr * 896 + 704 + 3 * (jt * 16 + c);
          out[base + 0] = ac[0][r];
          out[base + 1] = ac[1][r];
          out[base + 2] = ac[2][r];
        }
      }
    }
  }
}

extern "C" void kernel_launch(void* const* d_in, const int* in_sizes, int n_in,
                              void* d_out, int out_size, void* d_ws, size_t ws_size,
                              hipStream_t stream) {
  const float* in1   = (const float*)d_in[0];
  const float* in2   = (const float*)d_in[1];
  const float* Wa0   = (const float*)d_in[2];
  const float* Wb1o0 = (const float*)d_in[3];
  const float* Wa1   = (const float*)d_in[4];
  const float* Wb0   = (const float*)d_in[5];
  const float* Wo2   = (const float*)d_in[6];
  const float* bias  = (const float*)d_in[7];
  float* out = (float*)d_out;
  unsigned short* ws = (unsigned short*)d_ws;

  const int N = in_sizes[0] / 256;          // 100000

  hipLaunchKernelGGL(prep_weights, dim3(240), dim3(256), 0, stream,
                     Wa0, Wb1o0, Wa1, Wb0, Wo2, ws);
  const int nblocks = (N + 15) / 16;        // 6250
  hipLaunchKernelGGL(tp_main, dim3(nblocks), dim3(256), 0, stream,
                     in1, in2, bias, ws, out, N);
}

// Round 3
// 453.957 us; speedup vs baseline: 1.0347x; 1.0347x over previous
//
#include <hip/hip_runtime.h>

// TensorProduct: N=100000 rows, MUL=64. out[row] = concat(o0[320], o1[384], o2[192]).
// Key algebra: dot(v_b,v1) and cross(v_b,v1) are linear in v_b -> commute with the
// u-contraction. So ALL GEMMs are K=64 over {s_a, v_b[:,0..2]} and every per-row
// nonlinearity (s0, v1 mixing, cross) moves to the epilogue:
//   o0[w]   = bias + s0*(s_a@Wa0') + sum_c v1_c*(v_b[:,c]@Wb1o0')
//   o1[w,c] = v1_c*(s_a@Wa1') + s0*(v_b[:,c]@Wb0')
//   o2[w,:] = (v_b[:,:]@Wo2') x v1
// All scale factors fold to 1/sqrt(128) (o0 second term: /sqrt(384)), pre-applied.

typedef __bf16 v8bf __attribute__((ext_vector_type(8)));
typedef __bf16 v4bf __attribute__((ext_vector_type(4)));
typedef float f32x4 __attribute__((ext_vector_type(4)));

#define PW0f   0.08838834764831845f   // 1/sqrt(128)
#define PW0S3f 0.05103103630798288f   // 1/sqrt(384)

// ws layout (bf16 elements), all K=64 (KS=2 k-steps of 32):
//   Wa0'  [64x320] at 0       (20480)
//   Wb1o0'[64x320] at 20480   (20480)
//   Wa1'  [64x128] at 40960   ( 8192)
//   Wb0'  [64x128] at 49152   ( 8192)
//   Wo2'  [64x 64] at 57344   ( 4096)
// frag addr: B[k][n] -> (( (n>>4)*2 + (k>>5) )*64 + ((k>>3)&3)*16 + (n&15))*8 + (k&7)

__global__ __launch_bounds__(256) void prep_weights(
    const float* __restrict__ Wa0, const float* __restrict__ Wb1o0,
    const float* __restrict__ Wa1, const float* __restrict__ Wb0,
    const float* __restrict__ Wo2, unsigned short* __restrict__ ws) {
  int t = blockIdx.x * 256 + threadIdx.x;   // grid sized to exactly 61440
  float v; int k, n, base;
  if (t < 20480) {
    k = t / 320; n = t % 320; base = 0;     v = Wa0[k * 320 + n] * PW0f;
  } else if (t < 40960) {
    int tt = t - 20480; k = tt / 320; n = tt % 320; base = 20480; v = Wb1o0[k * 320 + n] * PW0S3f;
  } else if (t < 49152) {
    int tt = t - 40960; k = tt / 128; n = tt % 128; base = 40960; v = Wa1[k * 128 + n] * PW0f;
  } else if (t < 57344) {
    int tt = t - 49152; k = tt / 128; n = tt % 128; base = 49152; v = Wb0[k * 128 + n] * PW0f;
  } else {
    int tt = t - 57344; k = tt / 64;  n = tt % 64;  base = 57344; v = Wo2[k * 64 + n] * PW0f;
  }
  int nt = n >> 4, cc = n & 15, ks = k >> 5, qq = (k >> 3) & 3, j = k & 7;
  int addr = base + ((nt * 2 + ks) * 64 + qq * 16 + cc) * 8 + j;
  __bf16 h = (__bf16)v;
  ws[addr] = __builtin_bit_cast(unsigned short, h);
}

__global__ __launch_bounds__(256, 4) void tp_main(
    const float* __restrict__ in1, const float* __restrict__ in2,
    const float* __restrict__ bias, const unsigned short* __restrict__ wsb,
    float* __restrict__ out, int N) {
  // LDS: only bf16 A-fragment repacks + per-row scalars. 8.5 KB total.
  __shared__ __attribute__((aligned(16))) float s0v1[16 * 4];
  __shared__ __attribute__((aligned(16))) __bf16 fsa[1024];      // s_a     K=64, 16 rows
  __shared__ __attribute__((aligned(16))) __bf16 fvb[3][1024];   // v_b[:,c]

  const int tid = threadIdx.x;
  const int r0 = blockIdx.x * 16;

  // ---- Phase 1: direct global->reg->LDS fragment repack (no raw staging) ----
  {
    const int m = tid & 15;          // row within tile
    const int g = tid >> 4;          // u-group of 4: u = 4g..4g+3
    int rr = r0 + m; if (rr >= N) rr = N - 1;
    const float* rp = in1 + (size_t)rr * 256;
    const float4 sa4 = *(const float4*)(rp + 4 * g);
    const float4 w0  = *(const float4*)(rp + 64 + 12 * g);
    const float4 w1  = *(const float4*)(rp + 64 + 12 * g + 4);
    const float4 w2  = *(const float4*)(rp + 64 + 12 * g + 8);
    const float vf[12] = {w0.x, w0.y, w0.z, w0.w, w1.x, w1.y, w1.z, w1.w,
                          w2.x, w2.y, w2.z, w2.w};
    // A-frag slot for element (m, k): slot = (k>>5)*64 + ((k>>3)&3)*16 + m, j = k&7.
    // With k = 4g+i: slot = (g>>3)*64 + ((g>>1)&3)*16 + m, j = 4*(g&1)+i.
    // (R1 BUG was the missing (g>>3)*64 k-step term.)
    const int wbase = (((g >> 3) * 64 + ((g >> 1) & 3) * 16 + m) * 8) + 4 * (g & 1);
    v4bf pk;
    pk[0] = (__bf16)sa4.x; pk[1] = (__bf16)sa4.y; pk[2] = (__bf16)sa4.z; pk[3] = (__bf16)sa4.w;
    *(v4bf*)(fsa + wbase) = pk;
#pragma unroll
    for (int c3 = 0; c3 < 3; ++c3) {
      pk[0] = (__bf16)vf[c3]; pk[1] = (__bf16)vf[3 + c3];
      pk[2] = (__bf16)vf[6 + c3]; pk[3] = (__bf16)vf[9 + c3];
      *(v4bf*)(fvb[c3] + wbase) = pk;
    }
    if (tid < 16) {
      int rr2 = r0 + tid; if (rr2 >= N) rr2 = N - 1;
      *(float4*)(s0v1 + tid * 4) = *(const float4*)(in2 + (size_t)rr2 * 4);
    }
  }
  __syncthreads();

  // ---- Phase 2: MFMA jobs. A-fragments are job-invariant -> hoist them. ----
  const int lane = tid & 63;
  const int wv = tid >> 6;
  const int c = lane & 15, q = lane >> 4;

  v8bf a_sa[2], a_vb[3][2];
#pragma unroll
  for (int ks = 0; ks < 2; ++ks) {
    a_sa[ks] = *(const v8bf*)(fsa + (ks * 64 + lane) * 8);
#pragma unroll
    for (int c3 = 0; c3 < 3; ++c3)
      a_vb[c3][ks] = *(const v8bf*)(fvb[c3] + (ks * 64 + lane) * 8);
  }
  float4 sv[4];
#pragma unroll
  for (int r = 0; r < 4; ++r) sv[r] = *(const float4*)(s0v1 + (q * 4 + r) * 4);

  const unsigned short* Wa0p = wsb;
  const unsigned short* Wb1p = wsb + 20480;
  const unsigned short* Wa1p = wsb + 40960;
  const unsigned short* Wb0p = wsb + 49152;
  const unsigned short* Wo2p = wsb + 57344;

  for (int job = wv; job < 32; job += 4) {
    if (job < 20) {
      // ---- o0 tile nt: 8 MFMA (K=64 x {sa, vb0, vb1, vb2}) ----
      const int nt = job;
      v8bf wa0 = *(const v8bf*)(Wa0p + ((nt * 2 + 0) * 64 + lane) * 8);
      v8bf wa1 = *(const v8bf*)(Wa0p + ((nt * 2 + 1) * 64 + lane) * 8);
      v8bf wb0 = *(const v8bf*)(Wb1p + ((nt * 2 + 0) * 64 + lane) * 8);
      v8bf wb1 = *(const v8bf*)(Wb1p + ((nt * 2 + 1) * 64 + lane) * 8);
      f32x4 ta = {0.f, 0.f, 0.f, 0.f};
      f32x4 tb[3]; tb[0] = ta; tb[1] = ta; tb[2] = ta;
      ta = __builtin_amdgcn_mfma_f32_16x16x32_bf16(a_sa[0], wa0, ta, 0, 0, 0);
      ta = __builtin_amdgcn_mfma_f32_16x16x32_bf16(a_sa[1], wa1, ta, 0, 0, 0);
#pragma unroll
      for (int c3 = 0; c3 < 3; ++c3) {
        tb[c3] = __builtin_amdgcn_mfma_f32_16x16x32_bf16(a_vb[c3][0], wb0, tb[c3], 0, 0, 0);
        tb[c3] = __builtin_amdgcn_mfma_f32_16x16x32_bf16(a_vb[c3][1], wb1, tb[c3], 0, 0, 0);
      }
      const int col = nt * 16 + c;
      const float bv = bias[col];
#pragma unroll
      for (int r = 0; r < 4; ++r) {
        const int gr = r0 + q * 4 + r;
        if (gr < N)
          out[(size_t)gr * 896 + col] =
              bv + sv[r].x * ta[r] + sv[r].y * tb[0][r] + sv[r].z * tb[1][r] + sv[r].w * tb[2][r];
      }
    } else if (job < 28) {
      // ---- o1 tile jt: t1 = sa@Wa1', t2[c] = vb[c]@Wb0' (8 MFMA) ----
      const int jt = job - 20;
      v8bf ba0 = *(const v8bf*)(Wa1p + ((jt * 2 + 0) * 64 + lane) * 8);
      v8bf ba1 = *(const v8bf*)(Wa1p + ((jt * 2 + 1) * 64 + lane) * 8);
      v8bf bb0 = *(const v8bf*)(Wb0p + ((jt * 2 + 0) * 64 + lane) * 8);
      v8bf bb1 = *(const v8bf*)(Wb0p + ((jt * 2 + 1) * 64 + lane) * 8);
      f32x4 t1 = {0.f, 0.f, 0.f, 0.f};
      f32x4 t2[3]; t2[0] = t1; t2[1] = t1; t2[2] = t1;
      t1 = __builtin_amdgcn_mfma_f32_16x16x32_bf16(a_sa[0], ba0, t1, 0, 0, 0);
      t1 = __builtin_amdgcn_mfma_f32_16x16x32_bf16(a_sa[1], ba1, t1, 0, 0, 0);
#pragma unroll
      for (int c3 = 0; c3 < 3; ++c3) {
        t2[c3] = __builtin_amdgcn_mfma_f32_16x16x32_bf16(a_vb[c3][0], bb0, t2[c3], 0, 0, 0);
        t2[c3] = __builtin_amdgcn_mfma_f32_16x16x32_bf16(a_vb[c3][1], bb1, t2[c3], 0, 0, 0);
      }
#pragma unroll
      for (int r = 0; r < 4; ++r) {
        const int gr = r0 + q * 4 + r;
        if (gr < N) {
          const size_t base = (size_t)gr * 896 + 320 + 3 * (jt * 16 + c);
          out[base + 0] = t1[r] * sv[r].y + t2[0][r] * sv[r].x;
          out[base + 1] = t1[r] * sv[r].z + t2[1][r] * sv[r].x;
          out[base + 2] = t1[r] * sv[r].w + t2[2][r] * sv[r].x;
        }
      }
    } else {
      // ---- o2 tile jt: t3[c] = vb[c]@Wo2', epilogue cross(t3, v1) (6 MFMA) ----
      const int jt = job - 28;
      v8bf b0v = *(const v8bf*)(Wo2p + ((jt * 2 + 0) * 64 + lane) * 8);
      v8bf b1v = *(const v8bf*)(Wo2p + ((jt * 2 + 1) * 64 + lane) * 8);
      f32x4 t3[3];
      t3[0] = f32x4{0.f, 0.f, 0.f, 0.f}; t3[1] = t3[0]; t3[2] = t3[0];
#pragma unroll
      for (int c3 = 0; c3 < 3; ++c3) {
        t3[c3] = __builtin_amdgcn_mfma_f32_16x16x32_bf16(a_vb[c3][0], b0v, t3[c3], 0, 0, 0);
        t3[c3] = __builtin_amdgcn_mfma_f32_16x16x32_bf16(a_vb[c3][1], b1v, t3[c3], 0, 0, 0);
      }
#pragma unroll
      for (int r = 0; r < 4; ++r) {
        const int gr = r0 + q * 4 + r;
        if (gr < N) {
          const size_t base = (size_t)gr * 896 + 704 + 3 * (jt * 16 + c);
          out[base + 0] = t3[1][r] * sv[r].w - t3[2][r] * sv[r].z;
          out[base + 1] = t3[2][r] * sv[r].y - t3[0][r] * sv[r].w;
          out[base + 2] = t3[0][r] * sv[r].z - t3[1][r] * sv[r].y;
        }
      }
    }
  }
}

extern "C" void kernel_launch(void* const* d_in, const int* in_sizes, int n_in,
                              void* d_out, int out_size, void* d_ws, size_t ws_size,
                              hipStream_t stream) {
  const float* in1   = (const float*)d_in[0];
  const float* in2   = (const float*)d_in[1];
  const float* Wa0   = (const float*)d_in[2];
  const float* Wb1o0 = (const float*)d_in[3];
  const float* Wa1   = (const float*)d_in[4];
  const float* Wb0   = (const float*)d_in[5];
  const float* Wo2   = (const float*)d_in[6];
  const float* bias  = (const float*)d_in[7];
  float* out = (float*)d_out;
  unsigned short* ws = (unsigned short*)d_ws;

  const int N = in_sizes[0] / 256;          // 100000

  hipLaunchKernelGGL(prep_weights, dim3(240), dim3(256), 0, stream,
                     Wa0, Wb1o0, Wa1, Wb0, Wo2, ws);
  const int nblocks = (N + 15) / 16;        // 6250
  hipLaunchKernelGGL(tp_main, dim3(nblocks), dim3(256), 0, stream,
                     in1, in2, bias, ws, out, N);
}